// Round 6
// baseline (271.229 us; speedup 1.0000x reference)
//
#include <hip/hip_runtime.h>
#include <math.h>

#define WSZ 11
#define PAD 5
#define TX 128               // tile width (output cols per block)
#define RB 72                // output rows per block; 2160/72 = 30
#define CR 8                 // h-rows produced/consumed per tile
#define NTILE 11             // ceil((RB+2*PAD)/CR) = 82/8 -> 11 (tail rows harmless)
#define RX 4                 // h-pass: 4 output px per task
#define CHX (TX / RX)        // 32 x-chunks per row -> 8 rows x 32 = 256 tasks
#define SEG (RX + 2*PAD)     // 14 input floats per task
#define SA 129               // sH row stride in float4

typedef float v2f __attribute__((ext_vector_type(2)));

struct W11 { float w[WSZ]; };

// R11 sum/diff (4 channels, 2 pk_fma/tap) + R14 streaming vertical pass.
// R13 post-mortem: kernel was LDS-throughput-bound (~64% of cycles on the
// per-CU LDS pipe): Phase B re-read each h-row 4.33x (y-group halo overlap),
// Phase A writes had a lane-stride-64B 8-way bank conflict (~24 cyc/inst,
// the constant 9.98M counter), plus the shift phase. R14:
//  (1) streaming v-conv: each thread owns a column (2 threads/col via
//      channel split lo=(S,D) hi=(Qs,Qd)); 16-slot register ring of output
//      accumulators, scatter-accumulate per h-row, assign-on-first-tap.
//      Each h-row read ONCE (1 b64/px). No halo re-read -> no shift phase.
//  (2) j-major LDS slots (px 4cx+j -> slot j*32+cx): Phase A write lanes
//      consecutive 16B (conflict-free); Phase B owns columns through the
//      inverse permutation -> reads 64x8B contiguous (conflict-free).
//  (3) CR=8 tile: exactly 256 tasks -> 1 task/thread every tile, uniform.
// (R5 rerun: previous bench died on container infra, kernel unchanged.)
__global__ __launch_bounds__(256, 4) void ssim_l1_kernel(
    const float* __restrict__ pred, const float* __restrict__ targ,
    W11 wt, float2* __restrict__ partials)
{
    constexpr int H = 2160, W = 3840;
    __shared__ float4 sH[CR][SA];    // {hs, hd, hss, hdd} j-major slots, 16.5 KB

    const int c    = blockIdx.z;
    const int gx0  = blockIdx.x * TX;
    const int base = blockIdx.y * RB;
    const size_t plane = (size_t)H * W;
    const float* p = pred + (size_t)c * plane;
    const float* t = targ + (size_t)c * plane;

    const int tid = threadIdx.x;
    v2f loss_acc = {0.f, 0.f};       // .x = ssim (2x-counted), .y = l1
    const float C1v = 0.0001f, C2v = 0.0009f;

    // Phase A task identity (constant all tiles: 8 rows x 32 chunks = 256)
    const int rA  = tid >> 5;        // 0..7
    const int cxA = tid & 31;        // 0..31
    // Phase B identity: slot u = tid>>1, channel ch = tid&1
    const int u  = tid >> 1;         // 0..127 (contiguous LDS b64 reads)
    const int ch = tid & 1;          // 0: (S,D)  1: (Qs,Qd)
    const bool xfast = (blockIdx.x >= 1) && (blockIdx.x <= (W / TX) - 2);

    // register ring: 16 in-flight output accumulators (this thread's channel
    // pair). Statically indexed everywhere (rule: no runtime indexing).
    v2f ring[16];
    #pragma unroll
    for (int i = 0; i < 16; ++i) ring[i] = (v2f){0.f, 0.f};

    for (int s = 0; s < NTILE; ++s) {
        // ============ Phase A: horizontal 11-tap, global -> LDS ============
        {
            const int hr  = CR * s + rA;          // h-row index 0..87
            const int gy  = base - PAD + hr;      // global image row
            const int gxs = gx0 + cxA * RX - PAD; // input window e=0..13
            const bool rowok   = (gy >= 0) && (gy < H);
            const bool own_row = (gy >= base) && (gy < base + RB);

            float4 P[5], T[5];
            if (rowok && xfast) {
                const float4* p4 = (const float4*)(p + (size_t)gy * W + (gxs - 3));
                const float4* t4 = (const float4*)(t + (size_t)gy * W + (gxs - 3));
                #pragma unroll
                for (int i = 0; i < 5; ++i) { P[i] = p4[i]; T[i] = t4[i]; }
            } else if (rowok) {
                const size_t rowoff2 = (size_t)gy * W;
                #pragma unroll
                for (int i = 0; i < 5; ++i) {
                    float pe[4], te[4];
                    #pragma unroll
                    for (int q = 0; q < 4; ++q) {
                        int gx = gxs - 3 + 4 * i + q;
                        bool ok = (gx >= 0) && (gx < W);
                        pe[q] = ok ? p[rowoff2 + gx] : 0.f;
                        te[q] = ok ? t[rowoff2 + gx] : 0.f;
                    }
                    P[i] = make_float4(pe[0], pe[1], pe[2], pe[3]);
                    T[i] = make_float4(te[0], te[1], te[2], te[3]);
                }
            } else {
                #pragma unroll
                for (int i = 0; i < 5; ++i) {
                    P[i] = make_float4(0.f, 0.f, 0.f, 0.f);
                    T[i] = make_float4(0.f, 0.f, 0.f, 0.f);
                }
            }

            v2f h_sd[RX], h_qq[RX];
            #pragma unroll
            for (int j = 0; j < RX; ++j) {
                h_sd[j] = (v2f){0.f, 0.f};
                h_qq[j] = (v2f){0.f, 0.f};
            }
            #pragma unroll
            for (int e = 0; e < SEG; ++e) {
                const int ii = (e + 3) >> 2, qq = (e + 3) & 3;
                const float pe = (qq == 0) ? P[ii].x : (qq == 1) ? P[ii].y
                                : (qq == 2) ? P[ii].z : P[ii].w;
                const float te = (qq == 0) ? T[ii].x : (qq == 1) ? T[ii].y
                                : (qq == 2) ? T[ii].z : T[ii].w;
                v2f vsd; vsd.x = pe + te; vsd.y = pe - te;
                const v2f vsq = vsd * vsd;          // v_pk_mul_f32
                #pragma unroll
                for (int j = 0; j < RX; ++j) {
                    const int k = e - j;
                    if (k >= 0 && k < WSZ) {
                        const float wv = wt.w[k];
                        h_sd[j] += wv * vsd;        // v_pk_fma_f32
                        h_qq[j] += wv * vsq;        // v_pk_fma_f32
                    }
                }
                if (e >= PAD && e < PAD + RX && own_row)
                    loss_acc.y += fabsf(vsd.y);
            }
            // j-major slot: write inst j has lanes cxA consecutive -> 16B
            // stride -> conflict-free.
            #pragma unroll
            for (int j = 0; j < RX; ++j)
                sH[rA][j * 32 + cxA] = make_float4(h_sd[j].x, h_sd[j].y,
                                                   h_qq[j].x, h_qq[j].y);
        }
        __syncthreads();

        // ============ Phase B: streaming vertical 11-tap + SSIM ============
        // Parity-split so every ring index is a compile-time constant:
        // slot of output o is (o mod 16); hr mod 16 = r + (s odd ? 8 : 0).
        if (s & 1) {
            #pragma unroll
            for (int r = 0; r < CR; ++r) {
                const v2f* pv = reinterpret_cast<const v2f*>(&sH[r][u]);
                const v2f h = pv[ch];
                ring[(8 + r) & 15] = wt.w[0] * h;            // first tap: assign
                #pragma unroll
                for (int d = 1; d <= 10; ++d)
                    ring[(8 + r - d + 16) & 15] += wt.w[d] * h;
                const int o = CR * s + r - 10;               // wave-uniform
                if ((unsigned)o < (unsigned)RB) {
                    const v2f own = ring[(8 + r + 6) & 15];
                    v2f oth;
                    oth.x = __shfl_xor(own.x, 1, 64);
                    oth.y = __shfl_xor(own.y, 1, 64);
                    const v2f mu = ch ? oth : own;           // (S, D)
                    const v2f qv = ch ? own : oth;           // (Qs, Qd)
                    const v2f musq = mu * mu;
                    const v2f rr2  = qv - musq;
                    const float a    = 0.5f * (musq.x - musq.y) + C1v;
                    const float b    = 0.5f * (rr2.x - rr2.y) + C2v;
                    const float cden = 0.5f * (musq.x + musq.y) + C1v;
                    const float dden = 0.5f * (rr2.x + rr2.y) + C2v;
                    loss_acc.x += (a * b) * __builtin_amdgcn_rcpf(cden * dden);
                }
            }
        } else {
            #pragma unroll
            for (int r = 0; r < CR; ++r) {
                const v2f* pv = reinterpret_cast<const v2f*>(&sH[r][u]);
                const v2f h = pv[ch];
                ring[r & 15] = wt.w[0] * h;                  // first tap: assign
                #pragma unroll
                for (int d = 1; d <= 10; ++d)
                    ring[(r - d + 16) & 15] += wt.w[d] * h;
                const int o = CR * s + r - 10;
                if ((unsigned)o < (unsigned)RB) {
                    const v2f own = ring[(r + 6) & 15];
                    v2f oth;
                    oth.x = __shfl_xor(own.x, 1, 64);
                    oth.y = __shfl_xor(own.y, 1, 64);
                    const v2f mu = ch ? oth : own;
                    const v2f qv = ch ? own : oth;
                    const v2f musq = mu * mu;
                    const v2f rr2  = qv - musq;
                    const float a    = 0.5f * (musq.x - musq.y) + C1v;
                    const float b    = 0.5f * (rr2.x - rr2.y) + C2v;
                    const float cden = 0.5f * (musq.x + musq.y) + C1v;
                    const float dden = 0.5f * (rr2.x + rr2.y) + C2v;
                    loss_acc.x += (a * b) * __builtin_amdgcn_rcpf(cden * dden);
                }
            }
        }
        __syncthreads();   // Phase B reads done before next Phase A overwrites
    }

    // ============ block reduction -> contention-free partial ================
    #pragma unroll
    for (int off = 32; off > 0; off >>= 1) {
        loss_acc.x += __shfl_down(loss_acc.x, off, 64);
        loss_acc.y += __shfl_down(loss_acc.y, off, 64);
    }
    __shared__ float red[2][4];
    const int lane = tid & 63;
    const int wid  = tid >> 6;
    if (lane == 0) { red[0][wid] = loss_acc.x; red[1][wid] = loss_acc.y; }
    __syncthreads();
    if (tid == 0) {
        const float sv = red[0][0] + red[0][1] + red[0][2] + red[0][3];
        const float lv = red[1][0] + red[1][1] + red[1][2] + red[1][3];
        const int bid = (blockIdx.z * gridDim.y + blockIdx.y) * gridDim.x + blockIdx.x;
        partials[bid] = make_float2(sv, lv);
    }
}

__global__ __launch_bounds__(256) void finalize_kernel(
    const float2* __restrict__ partials, int n,
    float* __restrict__ out, double invN)
{
    const int tid = threadIdx.x;
    double s = 0.0, l = 0.0;
    for (int i = tid; i < n; i += 256) {
        float2 v = partials[i];
        s += (double)v.x;
        l += (double)v.y;
    }
    #pragma unroll
    for (int off = 32; off > 0; off >>= 1) {
        s += __shfl_down(s, off, 64);
        l += __shfl_down(l, off, 64);
    }
    __shared__ double rs[4], rl[4];
    const int lane = tid & 63, wid = tid >> 6;
    if (lane == 0) { rs[wid] = s; rl[wid] = l; }
    __syncthreads();
    if (tid == 0) {
        const double st = rs[0] + rs[1] + rs[2] + rs[3];
        const double lt = rl[0] + rl[1] + rl[2] + rl[3];
        // ssim partial is double-counted (both channel-threads emit identical
        // values), hence the 0.5 factor.
        out[0] = (float)(0.8 * lt * invN + 0.2 * (1.0 - 0.5 * st * invN));
    }
}

extern "C" void kernel_launch(void* const* d_in, const int* in_sizes, int n_in,
                              void* d_out, int out_size, void* d_ws, size_t ws_size,
                              hipStream_t stream)
{
    const float* pred = (const float*)d_in[0];
    const float* targ = (const float*)d_in[1];
    float* out = (float*)d_out;
    float2* partials = (float2*)d_ws;

    const int C = 3, H = 2160, W = 3840;

    W11 wt;
    double g[WSZ], sg = 0.0;
    for (int i = 0; i < WSZ; ++i) {
        double d = (double)i - (WSZ / 2);
        g[i] = exp(-(d * d) / (2.0 * 1.5 * 1.5));
        sg += g[i];
    }
    for (int i = 0; i < WSZ; ++i) wt.w[i] = (float)(g[i] / sg);

    dim3 grid(W / TX, H / RB, C);   // 30 x 30 x 3 = 2700 blocks
    ssim_l1_kernel<<<grid, 256, 0, stream>>>(pred, targ, wt, partials);

    const int nblocks = (W / TX) * (H / RB) * C;
    double invN = 1.0 / ((double)C * (double)H * (double)W);
    finalize_kernel<<<1, 256, 0, stream>>>(partials, nblocks, out, invN);
}

// Round 7
// 261.012 us; speedup vs baseline: 1.0391x; 1.0391x over previous
//
#include <hip/hip_runtime.h>
#include <math.h>

#define WSZ 11
#define PAD 5
#define TX 32
#define TY 24
#define NY 6                 // y-tiles per block: 144 rows/block, 2160/144 = 15
#define IY (TY + 2*PAD)      // 34
#define RX 4                 // h-pass: 4 output px per task
#define NTASK0 (IY * 8)      // 272 tasks (prologue: full 34 rows)
#define NTASK1 (TY * 8)      // 192 tasks (steady: 24 new rows)
#define SEG (RX + 2*PAD)     // 14 input floats per task
#define RY 3                 // v-pass rows per thread (8 groups x 3 = 24)
#define SA 33                // sH row stride in float4 (odd -> rotating banks)

typedef float v2f __attribute__((ext_vector_type(2)));

struct W11 { float w[WSZ]; };

// R11 base (sum/diff 4-channel, 2 pk_fma/tap; rolling halo; TX=32/TY=24/NY=6;
// 106us) + R15 single-barrier double-buffer.
// R14 post-mortem: killing ALL LDS conflicts + 4x LDS traffic made things
// WORSE (148us) because it added VALU; across R11-R14, VALUBusy x dur is
// constant -> the limiter is issue-rate, i.e. barrier/serialization stalls
// (17 barriers/block, strict A->B->shift chain). R15 changes ONLY the sync
// structure: two 34-row buffers; region s = { copy cur[24..33]->nxt[0..9];
// PhaseA(s+1)->nxt[10..33]; PhaseB(s)<-cur } then ONE barrier. A-writes
// never wait on B-readers; A's global loads issue before B's VALU burst
// (latency hidden); barriers 17 -> 7 per block. Per-px VALU, fetch, and
// write patterns are bit-identical to R11. LDS 35.9KB -> exactly 4 blocks/CU.
__global__ __launch_bounds__(256, 4) void ssim_l1_kernel(
    const float* __restrict__ pred, const float* __restrict__ targ,
    W11 wt, float2* __restrict__ partials)
{
    constexpr int H = 2160, W = 3840;
    __shared__ float4 sH[2][IY][SA];   // {hs, hd, hss, hdd} x2   35.9 KB

    const int c    = blockIdx.z;
    const int gx0  = blockIdx.x * TX;
    const int base = blockIdx.y * (TY * NY);   // first output row of block
    const size_t plane = (size_t)H * W;
    const float* p = pred + (size_t)c * plane;
    const float* t = targ + (size_t)c * plane;

    const int tid = threadIdx.x;
    v2f loss_acc = {0.f, 0.f};       // .x = ssim, .y = l1
    const float C1v = 0.0001f, C2v = 0.0009f;

    const int oxB  = tid & 31;
    const int oy0B = (tid >> 5) * RY;
    const bool xfast = (blockIdx.x >= 1) && (blockIdx.x <= (W / TX) - 2);

    // Phase A: horizontal 11-tap into dst. s==0: all 34 rows; s>0: rows 10..33.
    auto phaseA = [&](float4 (*__restrict__ dst)[SA], const int s) {
        const int ntask  = (s == 0) ? NTASK0 : NTASK1;
        const int rowoff = (s == 0) ? 0 : 2 * PAD;
        const int gyA    = base + TY * s - PAD;      // gy = gyA + rr
        for (int task = tid; task < ntask; task += 256) {
            const int r  = task >> 3;
            const int cx = task & 7;
            const int rr = rowoff + r;               // LDS buffer row
            const int gy = gyA + rr;                 // global image row
            const int gxs = gx0 + cx * RX - PAD;     // input window e=0..13
            const bool rowok   = (gy >= 0) && (gy < H);
            const bool own_row = (gy >= base) && (gy < base + TY * NY);

            // 5 aligned float4 per image covering gxs-3 .. gxs+16 (registers)
            float4 P[5], T[5];
            if (rowok && xfast) {
                const float4* p4 = (const float4*)(p + (size_t)gy * W + (gxs - 3));
                const float4* t4 = (const float4*)(t + (size_t)gy * W + (gxs - 3));
                #pragma unroll
                for (int i = 0; i < 5; ++i) { P[i] = p4[i]; T[i] = t4[i]; }
            } else if (rowok) {
                const size_t rowoff2 = (size_t)gy * W;
                #pragma unroll
                for (int i = 0; i < 5; ++i) {
                    float pe[4], te[4];
                    #pragma unroll
                    for (int q = 0; q < 4; ++q) {
                        int gx = gxs - 3 + 4 * i + q;
                        bool ok = (gx >= 0) && (gx < W);
                        pe[q] = ok ? p[rowoff2 + gx] : 0.f;
                        te[q] = ok ? t[rowoff2 + gx] : 0.f;
                    }
                    P[i] = make_float4(pe[0], pe[1], pe[2], pe[3]);
                    T[i] = make_float4(te[0], te[1], te[2], te[3]);
                }
            } else {
                #pragma unroll
                for (int i = 0; i < 5; ++i) {
                    P[i] = make_float4(0.f, 0.f, 0.f, 0.f);
                    T[i] = make_float4(0.f, 0.f, 0.f, 0.f);
                }
            }

            v2f h_sd[RX], h_qq[RX];
            #pragma unroll
            for (int j = 0; j < RX; ++j) {
                h_sd[j] = (v2f){0.f, 0.f};
                h_qq[j] = (v2f){0.f, 0.f};
            }
            #pragma unroll
            for (int e = 0; e < SEG; ++e) {
                const int ii = (e + 3) >> 2, qq = (e + 3) & 3;
                const float pe = (qq == 0) ? P[ii].x : (qq == 1) ? P[ii].y
                                : (qq == 2) ? P[ii].z : P[ii].w;
                const float te = (qq == 0) ? T[ii].x : (qq == 1) ? T[ii].y
                                : (qq == 2) ? T[ii].z : T[ii].w;
                v2f vsd; vsd.x = pe + te; vsd.y = pe - te;
                const v2f vsq = vsd * vsd;          // v_pk_mul_f32
                #pragma unroll
                for (int j = 0; j < RX; ++j) {
                    const int k = e - j;
                    if (k >= 0 && k < WSZ) {
                        const float wv = wt.w[k];
                        h_sd[j] += wv * vsd;        // v_pk_fma_f32
                        h_qq[j] += wv * vsq;        // v_pk_fma_f32
                    }
                }
                // L1 on owned pixels: each output row computed exactly once.
                if (e >= PAD && e < PAD + RX && own_row)
                    loss_acc.y += fabsf(vsd.y);
            }
            const int xb = cx * RX;
            #pragma unroll
            for (int j = 0; j < RX; ++j)
                dst[rr][xb + j] = make_float4(h_sd[j].x, h_sd[j].y,
                                              h_qq[j].x, h_qq[j].y);
        }
    };

    // ============ prologue: fill buffer 0 completely ========================
    phaseA(sH[0], 0);
    __syncthreads();

    for (int s = 0; s < NY; ++s) {
        float4 (*cur)[SA] = sH[s & 1];
        float4 (*nxt)[SA] = sH[(s & 1) ^ 1];

        if (s < NY - 1) {
            // halo copy: cur rows 24..33 -> nxt rows 0..9 (read-read with B)
            for (int i = tid; i < 2 * PAD * TX; i += 256) {   // 320 float4
                const int dr = i >> 5, cc = i & 31;
                nxt[dr][cc] = cur[dr + TY][cc];
            }
            // next tile's horizontal pass into nxt rows 10..33 (global loads
            // issue here, latency hidden under Phase B below)
            phaseA(nxt, s + 1);
        }

        // ============ Phase B: vertical 11-tap + SSIM (from cur) ===========
        {
            v2f mu[RY], qq[RY];
            #pragma unroll
            for (int j = 0; j < RY; ++j) {
                mu[j] = (v2f){0.f, 0.f};
                qq[j] = (v2f){0.f, 0.f};
            }
            #pragma unroll
            for (int k = 0; k < RY + 2 * PAD; ++k) {
                const float4 f = cur[oy0B + k][oxB];
                v2f fsd; fsd.x = f.x; fsd.y = f.y;
                v2f fsq; fsq.x = f.z; fsq.y = f.w;
                #pragma unroll
                for (int j = 0; j < RY; ++j) {
                    const int kk = k - j;
                    if (kk >= 0 && kk < WSZ) {
                        const float wv = wt.w[kk];
                        mu[j] += wv * fsd;          // v_pk_fma_f32
                        qq[j] += wv * fsq;          // v_pk_fma_f32
                    }
                }
            }
            #pragma unroll
            for (int j = 0; j < RY; ++j) {
                const v2f musq = mu[j] * mu[j];     // (S^2, D^2)  v_pk_mul
                const v2f rr2  = qq[j] - musq;      // (Qs-S^2, Qd-D^2)
                const float a    = 0.5f * (musq.x - musq.y) + C1v;
                const float b    = 0.5f * (rr2.x - rr2.y) + C2v;
                const float cden = 0.5f * (musq.x + musq.y) + C1v;
                const float dden = 0.5f * (rr2.x + rr2.y) + C2v;
                loss_acc.x += (a * b) * __builtin_amdgcn_rcpf(cden * dden);
            }
        }
        // ONE barrier per tile: guarantees (a) copy+A(s+1) writes to nxt done
        // before B(s+1) reads them; (b) B(s) reads of cur done before region
        // s+1 overwrites cur (as its nxt).
        __syncthreads();
    }

    // ============ block reduction -> contention-free partial ================
    #pragma unroll
    for (int off = 32; off > 0; off >>= 1) {
        loss_acc.x += __shfl_down(loss_acc.x, off, 64);
        loss_acc.y += __shfl_down(loss_acc.y, off, 64);
    }
    __shared__ float red[2][4];
    const int lane = tid & 63;
    const int wid  = tid >> 6;
    if (lane == 0) { red[0][wid] = loss_acc.x; red[1][wid] = loss_acc.y; }
    __syncthreads();
    if (tid == 0) {
        const float sv = red[0][0] + red[0][1] + red[0][2] + red[0][3];
        const float lv = red[1][0] + red[1][1] + red[1][2] + red[1][3];
        const int bid = (blockIdx.z * gridDim.y + blockIdx.y) * gridDim.x + blockIdx.x;
        partials[bid] = make_float2(sv, lv);
    }
}

__global__ __launch_bounds__(256) void finalize_kernel(
    const float2* __restrict__ partials, int n,
    float* __restrict__ out, double invN)
{
    const int tid = threadIdx.x;
    double s = 0.0, l = 0.0;
    for (int i = tid; i < n; i += 256) {
        float2 v = partials[i];
        s += (double)v.x;
        l += (double)v.y;
    }
    #pragma unroll
    for (int off = 32; off > 0; off >>= 1) {
        s += __shfl_down(s, off, 64);
        l += __shfl_down(l, off, 64);
    }
    __shared__ double rs[4], rl[4];
    const int lane = tid & 63, wid = tid >> 6;
    if (lane == 0) { rs[wid] = s; rl[wid] = l; }
    __syncthreads();
    if (tid == 0) {
        const double st = rs[0] + rs[1] + rs[2] + rs[3];
        const double lt = rl[0] + rl[1] + rl[2] + rl[3];
        out[0] = (float)(0.8 * lt * invN + 0.2 * (1.0 - st * invN));
    }
}

extern "C" void kernel_launch(void* const* d_in, const int* in_sizes, int n_in,
                              void* d_out, int out_size, void* d_ws, size_t ws_size,
                              hipStream_t stream)
{
    const float* pred = (const float*)d_in[0];
    const float* targ = (const float*)d_in[1];
    float* out = (float*)d_out;
    float2* partials = (float2*)d_ws;

    const int C = 3, H = 2160, W = 3840;

    W11 wt;
    double g[WSZ], sg = 0.0;
    for (int i = 0; i < WSZ; ++i) {
        double d = (double)i - (WSZ / 2);
        g[i] = exp(-(d * d) / (2.0 * 1.5 * 1.5));
        sg += g[i];
    }
    for (int i = 0; i < WSZ; ++i) wt.w[i] = (float)(g[i] / sg);

    dim3 grid(W / TX, H / (TY * NY), C);   // 120 x 15 x 3 = 5400 blocks
    ssim_l1_kernel<<<grid, 256, 0, stream>>>(pred, targ, wt, partials);

    const int nblocks = (W / TX) * (H / (TY * NY)) * C;
    double invN = 1.0 / ((double)C * (double)H * (double)W);
    finalize_kernel<<<1, 256, 0, stream>>>(partials, nblocks, out, invN);
}